// Round 12
// baseline (75.864 us; speedup 1.0000x reference)
//
#include <hip/hip_runtime.h>
#include <math.h>

#define NQ 12
#define TPB 256

// One 256-thread block (4 waves) per sample; 4096-amp state split 16-way:
// v[16] float2/thread = 32 VGPRs of state (fits the 64-VGPR cap the
// allocator pins at TPB>=256; R10/R11 verified no spill).
//
// Amp index j (12 bits), qubit q <-> j bit 11-q. Register layouts
// (t = thread 0..255 gives 8 bits, r = reg index 4 bits):
//   A: j = (r<<8)|t                  r = j[11:8] = qubits 0..3
//   B: j = (t[7:4]<<8)|(r<<4)|t[3:0] r = j[7:4]  = qubits 4..7
//   C: j = (t<<4)|r                  r = j[3:0]  = qubits 8..11
// B,C share wave bits j[11:10] -> B<->C roundtrips wave-local (no barrier).
// All LDS addresses strength-reduced (R11): sg and ring map P are GF(2)-
// linear; with kC=(t^(t>>4))&15:
//   sg(J_A(r)) = VA ^ 257r,  sg(J_B(r)) = VB ^ 17r,  sg(J_C(r)) = VC ^ r,
//   ring sg(P(j)) = Ft ^ G(r<<8) (G constant-folded).
//
// R12 changes (kernel is issue/latency-bound, R9-R11 evidence):
//  * barrier B5 REMOVED: post-ring read and A-write use the identical
//    per-thread address set ADDR_A(r); same-wave DS is in-order and
//    cross-thread sets are disjoint -> redundant. 7 -> 6 barriers.
//  * coefficient prefetch: per 2 gates, 3x ds_read_b128 -> one lgkmcnt
//    wait -> readfirstlane to SGPRs (was: per-gate scattered reads, each
//    with an exposed ~120-cyc wait). mB/coY packed into float4 pairs.
//  * WHT stages xor1/xor2 via DPP quad_perm (VALU pipe), off the DS pipe.
//
// Circuit (algebra verified R2-R11): init(C) = L0 RX product state with
// ring0 FOLDED via inverse perm; fused M_q = RX(L1)*RZ(L0)*RY(L0) in Euler
// form diag(1,e^{i psi}) RY(th) diag(1,e^{i phi}); ring1 scatter; L1 RY
// (final RZ dropped -- phase-only); <Z_q> via 6-stage WHT butterfly.

__device__ __forceinline__ float rfl(float x) {   // force wave-uniform -> SGPR
    return __int_as_float(__builtin_amdgcn_readfirstlane(__float_as_int(x)));
}

__device__ __forceinline__ float dpp_xor1(float x) {  // quad_perm [1,0,3,2]
    return __int_as_float(__builtin_amdgcn_update_dpp(
        0, __float_as_int(x), 0xB1, 0xF, 0xF, true));
}
__device__ __forceinline__ float dpp_xor2(float x) {  // quad_perm [2,3,0,1]
    return __int_as_float(__builtin_amdgcn_update_dpp(
        0, __float_as_int(x), 0x4E, 0xF, 0xF, true));
}

__device__ __forceinline__ float2 pk_mul(float2 a, float2 b) {
    float2 d;
    asm("v_pk_mul_f32 %0, %1, %2" : "=v"(d) : "v"(a), "v"(b));
    return d;
}
__device__ __forceinline__ float2 pk_fma(float2 a, float2 b, float2 c) {
    float2 d;
    asm("v_pk_fma_f32 %0, %1, %2, %3" : "=v"(d) : "v"(a), "v"(b), "v"(c));
    return d;
}

#define FOR_PAIRS4(RB, STMT) do {                                     \
    const int msk_ = 1 << (RB);                                       \
    _Pragma("unroll")                                                 \
    for (int h_ = 0; h_ < 8; ++h_) {                                  \
        const int i0 = ((h_ & ~(msk_ - 1)) << 1) | (h_ & (msk_ - 1)); \
        const int i1 = i0 | msk_;                                     \
        STMT;                                                         \
    } } while (0)

// strength-reduced swizzled addresses (VA/VB/VC in scope)
#define ADDR_A(r) (VA ^ (257 * (r)))
#define ADDR_B(r) (VB ^ (17 * (r)))
#define ADDR_C(r) (VC ^ (r))

// wave-local roundtrip (same-wave LDS ordering, no barrier)
#define LOCAL_X(AS, AD) do {                                          \
    _Pragma("unroll")                                                 \
    for (int r_ = 0; r_ < 16; ++r_) S[AS(r_)] = v[r_];                \
    _Pragma("unroll")                                                 \
    for (int r_ = 0; r_ < 16; ++r_) v[r_] = S[AD(r_)];                \
  } while (0)

// fused M_q as diag(1,e^{i psi}) RY(th) diag(1,e^{i phi}) -- scalar args
#define M_GATE_S(CT, ST, AZ, AW, PX, PY, RB) do {                           \
        float2 c2  = make_float2((CT), (CT));                               \
        float2 s2  = make_float2((ST), (ST));                               \
        float2 ms2 = make_float2(-(ST), -(ST));                             \
        FOR_PAIRS4(RB, {                                                    \
            float2 a1 = v[i1];                                              \
            float2 b1 = make_float2((AZ)*a1.x - (AW)*a1.y,                  \
                                    (AZ)*a1.y + (AW)*a1.x);                 \
            float2 n0 = pk_fma(b1, ms2, pk_mul(v[i0], c2));                 \
            float2 n1 = pk_fma(v[i0], s2, pk_mul(b1, c2));                  \
            v[i0] = n0;                                                     \
            v[i1] = make_float2((PX)*n1.x - (PY)*n1.y,                      \
                                (PX)*n1.y + (PY)*n1.x);                     \
        });                                                                 \
    } while (0)

#define RY_GATE_S(CT, ST, RB) do {                                          \
        float2 c2  = make_float2((CT), (CT));                               \
        float2 s2  = make_float2((ST), (ST));                               \
        float2 ms2 = make_float2(-(ST), -(ST));                             \
        FOR_PAIRS4(RB, {                                                    \
            float2 n0 = pk_fma(v[i1], ms2, pk_mul(v[i0], c2));              \
            float2 n1 = pk_fma(v[i0], s2, pk_mul(v[i1], c2));               \
            v[i0] = n0; v[i1] = n1;                                         \
        });                                                                 \
    } while (0)

// M phase: 2-gate batches -- 3x b128 load, one wait, rfl to SGPRs, compute
#define M_PHASE(QB) do {                                                    \
    _Pragma("unroll")                                                       \
    for (int g_ = 0; g_ < 2; ++g_) {                                        \
        const int q0_ = (QB) + 2 * g_;                                      \
        float4 A0 = mA[q0_], A1 = mA[q0_ + 1];                              \
        float4 Bp = mBp[q0_ >> 1];                                          \
        float c0_ = rfl(A0.x), s0_ = rfl(A0.y);                             \
        float z0_ = rfl(A0.z), w0_ = rfl(A0.w);                             \
        float c1_ = rfl(A1.x), s1_ = rfl(A1.y);                             \
        float z1_ = rfl(A1.z), w1_ = rfl(A1.w);                             \
        float p0x_ = rfl(Bp.x), p0y_ = rfl(Bp.y);                           \
        float p1x_ = rfl(Bp.z), p1y_ = rfl(Bp.w);                           \
        M_GATE_S(c0_, s0_, z0_, w0_, p0x_, p0y_, 3 - 2 * g_);               \
        M_GATE_S(c1_, s1_, z1_, w1_, p1x_, p1y_, 2 - 2 * g_);               \
    } } while (0)

// RY phase: 2x b128 = all 4 gates' (c,s)
#define RY_PHASE(QB) do {                                                   \
        float4 Y0 = coYp[(QB) >> 1], Y1 = coYp[((QB) >> 1) + 1];            \
        float ca_ = rfl(Y0.x), sa_ = rfl(Y0.y);                             \
        float cb_ = rfl(Y0.z), sb_ = rfl(Y0.w);                             \
        float cc_ = rfl(Y1.x), sc_ = rfl(Y1.y);                             \
        float cd_ = rfl(Y1.z), sd_ = rfl(Y1.w);                             \
        RY_GATE_S(ca_, sa_, 3); RY_GATE_S(cb_, sb_, 2);                     \
        RY_GATE_S(cc_, sc_, 1); RY_GATE_S(cd_, sd_, 0);                     \
    } while (0)

__global__ __launch_bounds__(TPB) void vqc_kernel(
    const float* __restrict__ x,    // [B, 12]
    const float* __restrict__ th,   // [2, 12, 2]
    const float* __restrict__ lm,   // [2, 12]
    float* __restrict__ out)        // [B, 12]
{
    __shared__ float2 S[4096];
    __shared__ float4 mA[12];
    __shared__ float4 mBp[6];       // (mB[2k], mB[2k+1]) packed
    __shared__ float2 coI[12];      // L0 RX half-angle (c,s)
    __shared__ float4 coYp[6];      // (coY[2k], coY[2k+1]) packed
    __shared__ float red[4 * 12];

    const int b = blockIdx.x;
    const int t = threadIdx.x;
    const int l = t & 63;
    const int w = t >> 6;

    // strength-reduced address bases
    const int kC = (t ^ (t >> 4)) & 15;
    const int VA = (t & 0xF0) | kC;
    const int VB = ((t >> 4) << 8) | kC;
    const int VC = (t << 4) | kC;
    // ring per-thread part: Ft = sg(P-image of t)
    int Ft;
    {
        int yt = t ^ (t >> 1); yt ^= yt >> 2; yt ^= yt >> 4; yt ^= yt >> 8;
        int pt = (yt & 0x7FF) | ((__popc(t) & 1) << 11);
        Ft = (pt & ~15) | ((pt ^ (pt >> 4) ^ (pt >> 8)) & 15);
    }

    // ---- cooperative coefficient precompute ----
    if (t < 12) {
        float h = 0.5f * lm[t] * x[b * NQ + t];
        float c, s; __sincosf(h, &s, &c);
        coI[t] = make_float2(c, s);
    } else if (t < 24) {
        int q = t - 12;
        float h = 0.5f * th[24 + 2 * q];
        float c, s; __sincosf(h, &s, &c);
        ((float2*)coYp)[q] = make_float2(c, s);
    } else if (t < 36) {
        int q = t - 24;
        float ha = 0.5f * lm[12 + q] * x[b * NQ + q];  // L1 RX half
        float hy = 0.5f * th[2 * q];                   // L0 RY half
        float hz = 0.5f * th[2 * q + 1];               // L0 RZ half
        float ca, sa, cy, sy, cz, sz;
        __sincosf(ha, &sa, &ca);
        __sincosf(hy, &sy, &cy);
        __sincosf(hz, &sz, &cz);
        // M = RX(a) RZ(z) RY(y) in SU(2): alpha = M00, beta = M10 (R9-verified)
        float ax = ca*cy*cz + sa*sy*sz;
        float ay = -(ca*cy*sz + sa*sy*cz);
        float bx = ca*sy*cz - sa*cy*sz;
        float by = ca*sy*sz - sa*cy*cz;
        float na = ax*ax + ay*ay, nb = bx*bx + by*by;
        float ra = rsqrtf(fmaxf(na, 1e-30f));
        float rb = rsqrtf(fmaxf(nb, 1e-30f));
        float ux = ax*ra, uy = ay*ra;
        float wx = bx*rb, wy = by*rb;
        mA[q] = make_float4(na*ra, nb*rb,
                            ux*wx - uy*wy, -(ux*wy + uy*wx));
        ((float2*)mBp)[q] = make_float2(ux*wx + uy*wy, ux*wy - uy*wx);
    }
    __syncthreads();                                   // B1

    float2 v[16];

    // ---- init in layout C: L0 RX product state, ring0 folded ----
    // (R10-verified) i = P^{-1}(j), j = (t<<4)|r:
    //  i0=r0^r1 (q11), i1=r1^r2 (q10), i2=r2^r3 (q9), i3=r3^t0 (q8),
    //  i4..i9 = gray(t) bits 0..5 (qubits 7..2),
    //  i10 = t6^r0^t7 (q1), i11 = r0^t7 (q0)
    {
        const int g = (t ^ (t >> 1)) & 0x3F;
        float Pt = 1.0f;
#pragma unroll
        for (int m = 0; m < 6; ++m) {
            float2 cs = coI[7 - m];
            Pt *= ((g >> m) & 1) ? cs.y : cs.x;
        }
        const int ct = __popc(g);
        const int t0 = t & 1, t7 = (t >> 7) & 1;
        const int e1 = ((t >> 6) ^ (t >> 7)) & 1;
        float2 q11 = coI[11], q10 = coI[10], q9 = coI[9],
               q8 = coI[8], q1 = coI[1], q0 = coI[0];
        const float u8  = t0 ? q8.y : q8.x;
        const float u8n = t0 ? q8.x : q8.y;
        const float u1  = e1 ? q1.y : q1.x;
        const float u1n = e1 ? q1.x : q1.y;
        const float u0  = t7 ? q0.y : q0.x;
        const float u0n = t7 ? q0.x : q0.y;
#pragma unroll
        for (int r = 0; r < 16; ++r) {
            const int r0 = r & 1, r1 = (r >> 1) & 1, r2 = (r >> 2) & 1,
                      r3 = (r >> 3) & 1;
            const int b11 = r0 ^ r1, b10 = r1 ^ r2, b9 = r2 ^ r3;
            float m = Pt * (b11 ? q11.y : q11.x) * (b10 ? q10.y : q10.x)
                         * (b9 ? q9.y : q9.x) * (r3 ? u8n : u8)
                         * (r0 ? u1n : u1) * (r0 ? u0n : u0);
            int k = (ct + b11 + b10 + b9 + (r3 ^ t0) + (r0 ^ e1) + (r0 ^ t7)) & 3;
            v[r].x = (k == 0) ? m : ((k == 2) ? -m : 0.0f);
            v[r].y = (k == 3) ? m : ((k == 1) ? -m : 0.0f);
        }
    }

    // ---- fused M-pass (L0 RY,RZ + L1 RX), C -> B -> A ----
    M_PHASE(8);                       // qubits 8..11 in C
    LOCAL_X(ADDR_C, ADDR_B);          // wave-local
    M_PHASE(4);                       // qubits 4..7  in B
#pragma unroll
    for (int r = 0; r < 16; ++r) S[ADDR_B(r)] = v[r];
    __syncthreads();                  // B2 (cross B -> A)
#pragma unroll
    for (int r = 0; r < 16; ++r) v[r] = S[ADDR_A(r)];
    M_PHASE(0);                       // qubits 0..3  in A

    // ---- layer-1 CNOT ring: A -> A (addr = Ft ^ const-folded G(r<<8)) ----
    __syncthreads();                  // B3 (all A-reads done before scatter)
#pragma unroll
    for (int r = 0; r < 16; ++r) {
        const int jr = r << 8;
        int yr = jr ^ (jr >> 1); yr ^= yr >> 2; yr ^= yr >> 4; yr ^= yr >> 8;
        const int pr = (yr & 0x7FF) | (((__popc(jr) ^ (jr >> 11)) & 1) << 11);
        const int Gr = (pr & ~15) | ((pr ^ (pr >> 4) ^ (pr >> 8)) & 15);
        S[Ft ^ Gr] = v[r];
    }
    __syncthreads();                  // B4
#pragma unroll
    for (int r = 0; r < 16; ++r) v[r] = S[ADDR_A(r)];

    // ---- layer-1 RY (final RZ dropped), A -> B -> C ----
    RY_PHASE(0);                      // in A
    // NO barrier here (was B5): this write set == own ring-read set
    // (ADDR_A(r), same thread); same-wave DS in-order, cross-thread
    // sets disjoint -> ordering guaranteed without sync.
#pragma unroll
    for (int r = 0; r < 16; ++r) S[ADDR_A(r)] = v[r];
    __syncthreads();                  // B6 (cross A -> B)
#pragma unroll
    for (int r = 0; r < 16; ++r) v[r] = S[ADDR_B(r)];
    RY_PHASE(4);                      // in B
    LOCAL_X(ADDR_B, ADDR_C);          // wave-local
    RY_PHASE(8);                      // in C

    // ---- measurement in C ----
    // qubits 8..11 <-> r bits 3..0 ; qubits 2..7 <-> lane bits 5..0
    // (lane bit k = j[4+k] = qubit 7-k) ; qubits 0,1 <-> wave bits 1,0
    float vals[5] = {0.f, 0.f, 0.f, 0.f, 0.f};  // ptot, z8, z9, z10, z11
#pragma unroll
    for (int r = 0; r < 16; ++r) {
        float p = fmaf(v[r].x, v[r].x, v[r].y * v[r].y);
        vals[0] += p;
        vals[1] += (r & 8) ? -p : p;
        vals[2] += (r & 4) ? -p : p;
        vals[3] += (r & 2) ? -p : p;
        vals[4] += (r & 1) ? -p : p;
    }
    // 6-stage WHT butterfly: lane L ends with sum_l (-1)^{popc(L&l)} x_l
    // stages 0,1 via DPP quad_perm (VALU pipe); 2..5 via shfl (DS pipe)
#pragma unroll
    for (int k = 0; k < 6; ++k) {
        const float sgn = ((l >> k) & 1) ? -1.f : 1.f;
#pragma unroll
        for (int m = 0; m < 5; ++m) {
            float tmp;
            if (k == 0)      tmp = dpp_xor1(vals[m]);
            else if (k == 1) tmp = dpp_xor2(vals[m]);
            else             tmp = __shfl_xor(vals[m], 1 << k, 64);
            vals[m] = fmaf(sgn, vals[m], tmp);
        }
    }
    if (l == 0) {                     // wave totals
        red[w * 12 + 0]  = vals[0];   // ptot (for qubits 0,1)
        red[w * 12 + 8]  = vals[1];
        red[w * 12 + 9]  = vals[2];
        red[w * 12 + 10] = vals[3];
        red[w * 12 + 11] = vals[4];
    } else if (__popc(l) == 1) {      // lane-bit sums: qubits 2..7
        int q = 8 - __ffs(l);         // l=1<<k -> q = 7-k
        red[w * 12 + q] = vals[0];
    }
    __syncthreads();                  // B7
    if (t < NQ) {
        float acc = 0.f;
#pragma unroll
        for (int ww = 0; ww < 4; ++ww) {
            if (t < 2) {
                float pv = red[ww * 12 + 0];
                acc += ((ww >> (1 - t)) & 1) ? -pv : pv;
            } else {
                acc += red[ww * 12 + t];
            }
        }
        out[b * NQ + t] = acc;
    }
}

extern "C" void kernel_launch(void* const* d_in, const int* in_sizes, int n_in,
                              void* d_out, int out_size, void* d_ws, size_t ws_size,
                              hipStream_t stream) {
    const int B = in_sizes[0] / NQ;  // 1024
    vqc_kernel<<<B, TPB, 0, stream>>>((const float*)d_in[0],
                                      (const float*)d_in[1],
                                      (const float*)d_in[2],
                                      (float*)d_out);
}

// Round 13
// 75.577 us; speedup vs baseline: 1.0038x; 1.0038x over previous
//
#include <hip/hip_runtime.h>
#include <math.h>

#define NQ 12
#define TPB 256

// FINAL (R13 = R11, the empirically best variant; R12's micro-changes
// measured neutral-to-negative and were reverted).
//
// One 256-thread block (4 waves) per sample; 4096-amp state split 16-way:
// v[16] float2/thread = 32 VGPRs of state (fits the 64-VGPR cap the
// allocator pins at TPB>=256; verified no spill, VGPR_Count=52).
//
// Amp index j (12 bits), qubit q <-> j bit 11-q. Register layouts
// (t = thread 0..255 gives 8 bits, r = reg index 4 bits):
//   A: j = (r<<8)|t                  r = j[11:8] = qubits 0..3
//   B: j = (t[7:4]<<8)|(r<<4)|t[3:0] r = j[7:4]  = qubits 4..7
//   C: j = (t<<4)|r                  r = j[3:0]  = qubits 8..11
// B,C share wave bits j[11:10] -> B<->C roundtrips wave-local (no barrier).
//
// All LDS addresses strength-reduced: sg(j)=(j&~15)|((j^(j>>4)^(j>>8))&15)
// and the ring map P are GF(2)-linear, so with kC=(t^(t>>4))&15:
//   sg(J_A(r)) = VA ^ 257r,  VA = (t&0xF0)|kC
//   sg(J_B(r)) = VB ^ 17r,   VB = ((t>>4)<<8)|kC
//   sg(J_C(r)) = VC ^ r,     VC = (t<<4)|kC
//   sg(P(j))   = Ft ^ G(r<<8), Ft per-thread, G constant-folded
//
// Circuit (algebra verified R2-R12): init(C) = L0 RX product state with
// ring0 FOLDED via inverse perm; fused M_q = RX(L1)*RZ(L0)*RY(L0) in Euler
// form diag(1,e^{i psi}) RY(th) diag(1,e^{i phi}); ring1 scatter; L1 RY
// (final RZ dropped -- phase-only); <Z_q> via 6-stage WHT butterfly.
//
// Ceiling note (R7-R12 evidence): dispatch ~22.5us vs ~10us VALU/DS floor;
// the gap is serial LDS roundtrip latency at LDS-capped 4 blocks/CU. Six
// independent stall-attack levers converged here; bench additionally
// carries ~52us of harness re-poison overhead.

__device__ __forceinline__ float rfl(float x) {   // force wave-uniform -> SGPR
    return __int_as_float(__builtin_amdgcn_readfirstlane(__float_as_int(x)));
}

__device__ __forceinline__ float2 pk_mul(float2 a, float2 b) {
    float2 d;
    asm("v_pk_mul_f32 %0, %1, %2" : "=v"(d) : "v"(a), "v"(b));
    return d;
}
__device__ __forceinline__ float2 pk_fma(float2 a, float2 b, float2 c) {
    float2 d;
    asm("v_pk_fma_f32 %0, %1, %2, %3" : "=v"(d) : "v"(a), "v"(b), "v"(c));
    return d;
}

#define FOR_PAIRS4(RB, STMT) do {                                     \
    const int msk_ = 1 << (RB);                                       \
    _Pragma("unroll")                                                 \
    for (int h_ = 0; h_ < 8; ++h_) {                                  \
        const int i0 = ((h_ & ~(msk_ - 1)) << 1) | (h_ & (msk_ - 1)); \
        const int i1 = i0 | msk_;                                     \
        STMT;                                                         \
    } } while (0)

// strength-reduced swizzled addresses (VA/VB/VC/kC in scope)
#define ADDR_A(r) (VA ^ (257 * (r)))
#define ADDR_B(r) (VB ^ (17 * (r)))
#define ADDR_C(r) (VC ^ (r))

// wave-local roundtrip (same-wave LDS ordering, no barrier)
#define LOCAL_X(AS, AD) do {                                          \
    _Pragma("unroll")                                                 \
    for (int r_ = 0; r_ < 16; ++r_) S[AS(r_)] = v[r_];                \
    _Pragma("unroll")                                                 \
    for (int r_ = 0; r_ < 16; ++r_) v[r_] = S[AD(r_)];                \
  } while (0)

// fused M_q as diag(1,e^{i psi}) RY(th) diag(1,e^{i phi})
// mA[q] = (cth, sth, psi.x, psi.y) ; mB[q] = (phi.x, phi.y)
#define M_GATE(q, RB) do {                                                  \
        float4 A4v = mA[q]; float2 P2v = mB[q];                             \
        float az = rfl(A4v.z), aw = rfl(A4v.w);                             \
        float px = rfl(P2v.x), py = rfl(P2v.y);                             \
        float cth = rfl(A4v.x), sth = rfl(A4v.y);                           \
        float2 c2  = make_float2(cth, cth);                                 \
        float2 s2  = make_float2(sth, sth);                                 \
        float2 ms2 = make_float2(-sth, -sth);                               \
        FOR_PAIRS4(RB, {                                                    \
            float2 a1 = v[i1];                                              \
            float2 b1 = make_float2(az*a1.x - aw*a1.y,                      \
                                    az*a1.y + aw*a1.x);                     \
            float2 n0 = pk_fma(b1, ms2, pk_mul(v[i0], c2));                 \
            float2 n1 = pk_fma(v[i0], s2, pk_mul(b1, c2));                  \
            v[i0] = n0;                                                     \
            v[i1] = make_float2(px*n1.x - py*n1.y,                          \
                                px*n1.y + py*n1.x);                         \
        });                                                                 \
    } while (0)

#define RY_GATE(q, RB) do {                                                 \
        float2 csv = coY[q];                                                \
        float cth = rfl(csv.x), sth = rfl(csv.y);                           \
        float2 c2  = make_float2(cth, cth);                                 \
        float2 s2  = make_float2(sth, sth);                                 \
        float2 ms2 = make_float2(-sth, -sth);                               \
        FOR_PAIRS4(RB, {                                                    \
            float2 n0 = pk_fma(v[i1], ms2, pk_mul(v[i0], c2));              \
            float2 n1 = pk_fma(v[i0], s2, pk_mul(v[i1], c2));               \
            v[i0] = n0; v[i1] = n1;                                         \
        });                                                                 \
    } while (0)

// phase: gate qubit QB+d on r-bit 3-d (holds for A, B, C alike)
#define M_PHASE(QB)  do { _Pragma("unroll")                                 \
    for (int d_ = 0; d_ < 4; ++d_) M_GATE((QB) + d_, 3 - d_); } while (0)
#define RY_PHASE(QB) do { _Pragma("unroll")                                 \
    for (int d_ = 0; d_ < 4; ++d_) RY_GATE((QB) + d_, 3 - d_); } while (0)

__global__ __launch_bounds__(TPB) void vqc_kernel(
    const float* __restrict__ x,    // [B, 12]
    const float* __restrict__ th,   // [2, 12, 2]
    const float* __restrict__ lm,   // [2, 12]
    float* __restrict__ out)        // [B, 12]
{
    __shared__ float2 S[4096];
    __shared__ float4 mA[12];
    __shared__ float2 mB[12];
    __shared__ float2 coI[12];      // L0 RX half-angle (c,s)
    __shared__ float2 coY[12];      // L1 RY half-angle (c,s)
    __shared__ float red[4 * 12];

    const int b = blockIdx.x;
    const int t = threadIdx.x;
    const int l = t & 63;
    const int w = t >> 6;

    // strength-reduced address bases
    const int kC = (t ^ (t >> 4)) & 15;
    const int VA = (t & 0xF0) | kC;
    const int VB = ((t >> 4) << 8) | kC;
    const int VC = (t << 4) | kC;
    // ring per-thread part: Ft = sg(P-image of t) (GF(2)-linear split)
    int Ft;
    {
        int yt = t ^ (t >> 1); yt ^= yt >> 2; yt ^= yt >> 4; yt ^= yt >> 8;
        int pt = (yt & 0x7FF) | ((__popc(t) & 1) << 11);
        Ft = (pt & ~15) | ((pt ^ (pt >> 4) ^ (pt >> 8)) & 15);
    }

    // ---- cooperative coefficient precompute ----
    if (t < 12) {
        float h = 0.5f * lm[t] * x[b * NQ + t];
        float c, s; __sincosf(h, &s, &c);
        coI[t] = make_float2(c, s);
    } else if (t < 24) {
        int q = t - 12;
        float h = 0.5f * th[24 + 2 * q];
        float c, s; __sincosf(h, &s, &c);
        coY[q] = make_float2(c, s);
    } else if (t < 36) {
        int q = t - 24;
        float ha = 0.5f * lm[12 + q] * x[b * NQ + q];  // L1 RX half
        float hy = 0.5f * th[2 * q];                   // L0 RY half
        float hz = 0.5f * th[2 * q + 1];               // L0 RZ half
        float ca, sa, cy, sy, cz, sz;
        __sincosf(ha, &sa, &ca);
        __sincosf(hy, &sy, &cy);
        __sincosf(hz, &sz, &cz);
        // M = RX(a) RZ(z) RY(y) in SU(2): alpha = M00, beta = M10
        float ax = ca*cy*cz + sa*sy*sz;
        float ay = -(ca*cy*sz + sa*sy*cz);
        float bx = ca*sy*cz - sa*cy*sz;
        float by = ca*sy*sz - sa*cy*cz;
        float na = ax*ax + ay*ay, nb = bx*bx + by*by;
        float ra = rsqrtf(fmaxf(na, 1e-30f));
        float rb = rsqrtf(fmaxf(nb, 1e-30f));
        float ux = ax*ra, uy = ay*ra;
        float wx = bx*rb, wy = by*rb;
        mA[q] = make_float4(na*ra, nb*rb,
                            ux*wx - uy*wy, -(ux*wy + uy*wx));
        mB[q] = make_float2(ux*wx + uy*wy, ux*wy - uy*wx);
    }
    __syncthreads();                                   // B1

    float2 v[16];

    // ---- init in layout C: L0 RX product state, ring0 folded ----
    // i = P^{-1}(j), j = (t<<4)|r:
    //  i0=r0^r1 (q11), i1=r1^r2 (q10), i2=r2^r3 (q9), i3=r3^t0 (q8),
    //  i4..i9 = gray(t) bits 0..5 (qubits 7..2),
    //  i10 = t6^r0^t7 (q1), i11 = r0^t7 (q0)
    {
        const int g = (t ^ (t >> 1)) & 0x3F;
        float Pt = 1.0f;
#pragma unroll
        for (int m = 0; m < 6; ++m) {
            float2 cs = coI[7 - m];
            Pt *= ((g >> m) & 1) ? cs.y : cs.x;
        }
        const int ct = __popc(g);
        const int t0 = t & 1, t7 = (t >> 7) & 1;
        const int e1 = ((t >> 6) ^ (t >> 7)) & 1;
        float2 q11 = coI[11], q10 = coI[10], q9 = coI[9],
               q8 = coI[8], q1 = coI[1], q0 = coI[0];
        const float u8  = t0 ? q8.y : q8.x;     // qubit 8, key t0^r3
        const float u8n = t0 ? q8.x : q8.y;
        const float u1  = e1 ? q1.y : q1.x;     // qubit 1, key e1^r0
        const float u1n = e1 ? q1.x : q1.y;
        const float u0  = t7 ? q0.y : q0.x;     // qubit 0, key t7^r0
        const float u0n = t7 ? q0.x : q0.y;
#pragma unroll
        for (int r = 0; r < 16; ++r) {
            const int r0 = r & 1, r1 = (r >> 1) & 1, r2 = (r >> 2) & 1,
                      r3 = (r >> 3) & 1;
            const int b11 = r0 ^ r1, b10 = r1 ^ r2, b9 = r2 ^ r3;
            float m = Pt * (b11 ? q11.y : q11.x) * (b10 ? q10.y : q10.x)
                         * (b9 ? q9.y : q9.x) * (r3 ? u8n : u8)
                         * (r0 ? u1n : u1) * (r0 ? u0n : u0);
            int k = (ct + b11 + b10 + b9 + (r3 ^ t0) + (r0 ^ e1) + (r0 ^ t7)) & 3;
            v[r].x = (k == 0) ? m : ((k == 2) ? -m : 0.0f);
            v[r].y = (k == 3) ? m : ((k == 1) ? -m : 0.0f);
        }
    }

    // ---- fused M-pass (L0 RY,RZ + L1 RX), C -> B -> A ----
    M_PHASE(8);                       // qubits 8..11 in C
    LOCAL_X(ADDR_C, ADDR_B);          // wave-local
    M_PHASE(4);                       // qubits 4..7  in B
#pragma unroll
    for (int r = 0; r < 16; ++r) S[ADDR_B(r)] = v[r];
    __syncthreads();                  // B2 (cross B -> A)
#pragma unroll
    for (int r = 0; r < 16; ++r) v[r] = S[ADDR_A(r)];
    M_PHASE(0);                       // qubits 0..3  in A

    // ---- layer-1 CNOT ring: A -> A (addr = Ft ^ const-folded G(r<<8)) ----
    __syncthreads();                  // B3 (all A-reads done)
#pragma unroll
    for (int r = 0; r < 16; ++r) {
        const int jr = r << 8;
        int yr = jr ^ (jr >> 1); yr ^= yr >> 2; yr ^= yr >> 4; yr ^= yr >> 8;
        const int pr = (yr & 0x7FF) | (((__popc(jr) ^ (jr >> 11)) & 1) << 11);
        const int Gr = (pr & ~15) | ((pr ^ (pr >> 4) ^ (pr >> 8)) & 15);
        S[Ft ^ Gr] = v[r];
    }
    __syncthreads();                  // B4
#pragma unroll
    for (int r = 0; r < 16; ++r) v[r] = S[ADDR_A(r)];

    // ---- layer-1 RY (final RZ dropped), A -> B -> C ----
    RY_PHASE(0);                      // in A
    __syncthreads();                  // B5 (all ring-reads done)
#pragma unroll
    for (int r = 0; r < 16; ++r) S[ADDR_A(r)] = v[r];
    __syncthreads();                  // B6 (cross A -> B)
#pragma unroll
    for (int r = 0; r < 16; ++r) v[r] = S[ADDR_B(r)];
    RY_PHASE(4);                      // in B
    LOCAL_X(ADDR_B, ADDR_C);          // wave-local
    RY_PHASE(8);                      // in C

    // ---- measurement in C ----
    // qubits 8..11 <-> r bits 3..0 ; qubits 2..7 <-> lane bits 5..0
    // (lane bit k = j[4+k] = qubit 7-k) ; qubits 0,1 <-> wave bits 1,0
    float vals[5] = {0.f, 0.f, 0.f, 0.f, 0.f};  // ptot, z8, z9, z10, z11
#pragma unroll
    for (int r = 0; r < 16; ++r) {
        float p = fmaf(v[r].x, v[r].x, v[r].y * v[r].y);
        vals[0] += p;
        vals[1] += (r & 8) ? -p : p;
        vals[2] += (r & 4) ? -p : p;
        vals[3] += (r & 2) ? -p : p;
        vals[4] += (r & 1) ? -p : p;
    }
    // 6-stage WHT butterfly: lane L ends with sum_l (-1)^{popc(L&l)} x_l
#pragma unroll
    for (int k = 0; k < 6; ++k) {
        const float sgn = ((l >> k) & 1) ? -1.f : 1.f;
#pragma unroll
        for (int m = 0; m < 5; ++m) {
            float tmp = __shfl_xor(vals[m], 1 << k, 64);
            vals[m] = fmaf(sgn, vals[m], tmp);
        }
    }
    if (l == 0) {                     // wave totals
        red[w * 12 + 0]  = vals[0];   // ptot (for qubits 0,1)
        red[w * 12 + 8]  = vals[1];
        red[w * 12 + 9]  = vals[2];
        red[w * 12 + 10] = vals[3];
        red[w * 12 + 11] = vals[4];
    } else if (__popc(l) == 1) {      // lane-bit sums: qubits 2..7
        int q = 8 - __ffs(l);         // l=1<<k -> q = 7-k
        red[w * 12 + q] = vals[0];
    }
    __syncthreads();                  // B7
    if (t < NQ) {
        float acc = 0.f;
#pragma unroll
        for (int ww = 0; ww < 4; ++ww) {
            if (t < 2) {
                float pv = red[ww * 12 + 0];
                acc += ((ww >> (1 - t)) & 1) ? -pv : pv;
            } else {
                acc += red[ww * 12 + t];
            }
        }
        out[b * NQ + t] = acc;
    }
}

extern "C" void kernel_launch(void* const* d_in, const int* in_sizes, int n_in,
                              void* d_out, int out_size, void* d_ws, size_t ws_size,
                              hipStream_t stream) {
    const int B = in_sizes[0] / NQ;  // 1024
    vqc_kernel<<<B, TPB, 0, stream>>>((const float*)d_in[0],
                                      (const float*)d_in[1],
                                      (const float*)d_in[2],
                                      (float*)d_out);
}